// Round 4
// baseline (84.259 us; speedup 1.0000x reference)
//
#include <hip/hip_runtime.h>

// BezierToImageLayer as a sparse-fill MFMA GEMM.
// result[b,i,j] = clamp(sum_k gx[k][i]*gy[k][j]) with k = 4800 splats:
// a 64x64x4800 f16 GEMM per sample. Gx/Gy are 6-sparse per column (alpha=2e-4
// -> 6-tap window, error ~2e-3 << 2e-2) and built in LDS with plain
// ds_write_b16 (each splat owns its k-column -> NO atomics).
//
// R4: OUTPUT-ROW SPLIT for occupancy. R0 counters showed latency-bound
// (Occupancy 7.4% = 1 wave/SIMD, VALUBusy 26%, MfmaUtil 8%); R3 proved
// intra-wave pipelining is already done by the compiler (null result), so
// the fix must be co-resident waves. Two earlier occupancy attempts failed
// with absmax~1.0 (= output never written): R1 used 128 KiB *static* LDS
// (launch suspect), R2 depended on d_ws. This version keeps every verified
// constraint: single kernel, no workspace, 256-thread block, <=64 KiB static
// LDS, direct clamped stores. Grid = 2 blocks/sample; block z owns tile rows
// [32z, 32z+32) (image rows 30z-2 .. 30z+29): gx tile is 32x64 with taps
// CLIPPED to the block's row range, gy stays 64x64 (tap work duplicated x2 -
// acceptable: VALU floor ~21us << the 41us latency bill). Each block runs
// ALL 75 K-chunks -> partial-free: its clamped stores cover a disjoint
// image-row range exactly once. LDS = 4 waves x (4KB gx + 8KB gy) = 48 KiB;
// 2 blocks/CU co-resident = 2 waves/SIMD.
//
// Tile row r = image row r-2 (C rows 2..61 are the 60 output pixels); splat
// windows reaching image rows 62/63 are clamped into tile row 63 (discarded).

#define WIDTH 60
#define LCURVES 160
#define NSAMP 30
#define NEG_INVA_LOG2E (-7213.4752f)   // -(1/alpha)*log2(e) = -5000*1.442695

typedef _Float16 half8 __attribute__((ext_vector_type(8)));
typedef float floatx4 __attribute__((ext_vector_type(4)));

__global__ __launch_bounds__(256) void bezier_mfma_kernel(
    const float* __restrict__ x, float* __restrict__ out) {
    // 4 waves x (gx 32x64 + gy 64x64) f16 = 49152 B; reused for reduction.
    __shared__ __align__(16) char smem[49152];

    const int tid = threadIdx.x;
    const int lane = tid & 63;
    const int w = tid >> 6;          // wave id 0..3
    const int b = blockIdx.x >> 1;   // sample
    const int z = blockIdx.x & 1;    // row-half id
    const int base = z << 5;         // first tile row this block owns (0 / 32)
    const int m = lane & 15;         // fragment row/col within 16
    const int q = lane >> 4;         // quad 0..3

    // zero all tiles (3072 float4s)
    float4* sz = (float4*)smem;
#pragma unroll
    for (int i = 0; i < 12; ++i)
        sz[tid + 256 * i] = make_float4(0.f, 0.f, 0.f, 0.f);
    __syncthreads();

    _Float16* gx = (_Float16*)(smem + w * 12288);         // [32][64] swizzled
    _Float16* gy = (_Float16*)(smem + w * 12288 + 4096);  // [64][64] swizzled

    floatx4 acc[2][4];
#pragma unroll
    for (int ti = 0; ti < 2; ++ti)
#pragma unroll
        for (int tj = 0; tj < 4; ++tj)
            acc[ti][tj] = (floatx4){0.f, 0.f, 0.f, 0.f};

    const float* xb = x + (size_t)b * (LCURVES * 8);
    int prev_i0 = 0, prev_j0 = 0;   // first-iter zeroing hits already-zero cells

    // 75 chunks of 64 splats; wave w takes chunks w, w+4, ... (disjoint K).
    // Both row-half blocks traverse ALL chunks.
    for (int c = w; c < 75; c += 4) {
        int s = c * 64 + lane;            // this lane's splat = its k-column
        int l = s % LCURVES;
        int n = s / LCURVES;

        const float4* cp = (const float4*)(xb + l * 8);
        float4 c0 = cp[0];  // x0 y0 x1 y1
        float4 c1 = cp[1];  // x2 y2 x3 y3

        // warped Bernstein basis (matches reference _bezier_basis)
        float tt = (float)n * (1.0f / NSAMP);
        tt = 2.0f * tt * tt * tt - 3.0f * tt * tt + 2.0f * tt;
        float tb = 1.0f - tt, t2 = tt * tt;
        float w0 = t2 * tt;
        float w1 = 3.0f * (t2 - w0);
        float w2 = 3.0f * tt * tb * tb;
        float w3 = tb * tb * tb;
        float X = w0 * c0.x + w1 * c0.z + w2 * c1.x + w3 * c1.z;
        float Y = w0 * c0.y + w1 * c0.w + w2 * c1.y + w3 * c1.w;

        int i0 = (int)floorf(X * (float)WIDTH);
        int j0 = (int)floorf(Y * (float)WIDTH);
        i0 = min(max(i0, 0), 59);
        j0 = min(max(j0, 0), 59);

        // zero previous chunk's cells (same lane, in-order DS -> safe); gx
        // rows are clipped to this block's 32-row window with IDENTICAL math
        // to the write below, so the zeroed set == the written set.
#pragma unroll
        for (int a = 0; a < 6; ++a) {
            int rz = min(prev_i0 + a, 63) - base;
            if ((unsigned)rz < 32u)
                gx[rz * 64 + (lane ^ ((rz & 7) << 3))] = (_Float16)0;
            int rz2 = min(prev_j0 + a, 63);
            gy[rz2 * 64 + (lane ^ ((rz2 & 7) << 3))] = (_Float16)0;
        }
        float bx = (float)(i0 - 2) * (1.0f / WIDTH) - X;
        float by = (float)(j0 - 2) * (1.0f / WIDTH) - Y;
#pragma unroll
        for (int a = 0; a < 6; ++a) {
            float dx = bx + (float)a * (1.0f / WIDTH);
            float vx = __builtin_amdgcn_exp2f(dx * dx * NEG_INVA_LOG2E);
            int r = min(i0 + a, 63) - base;
            if ((unsigned)r < 32u)
                gx[r * 64 + (lane ^ ((r & 7) << 3))] = (_Float16)vx;
            float dy = by + (float)a * (1.0f / WIDTH);
            float vy = __builtin_amdgcn_exp2f(dy * dy * NEG_INVA_LOG2E);
            int r2 = min(j0 + a, 63);
            gy[r2 * 64 + (lane ^ ((r2 & 7) << 3))] = (_Float16)vy;
        }
        prev_i0 = i0;
        prev_j0 = j0;

        // MFMA over this chunk's K=64: A[m][k]=gx(local row m)[k],
        // B[k][n]=gy(row n)[k]. Lane(m,q) holds k = kk*32 + q*8 + j;
        // swizzled col base = 8*((kk*4+q) ^ (row&7)) -> ds_read_b128.
#pragma unroll
        for (int kk = 0; kk < 2; ++kk) {
            half8 af[2], bf[4];
#pragma unroll
            for (int t = 0; t < 2; ++t) {
                int ra = t * 16 + m;
                af[t] = *(const half8*)&gx[ra * 64 + (((kk * 4 + q) ^ (ra & 7)) << 3)];
            }
#pragma unroll
            for (int t = 0; t < 4; ++t) {
                int rb = t * 16 + m;
                bf[t] = *(const half8*)&gy[rb * 64 + (((kk * 4 + q) ^ (rb & 7)) << 3)];
            }
#pragma unroll
            for (int ti = 0; ti < 2; ++ti)
#pragma unroll
                for (int tj = 0; tj < 4; ++tj)
                    acc[ti][tj] = __builtin_amdgcn_mfma_f32_16x16x32_f16(
                        af[ti], bf[tj], acc[ti][tj], 0, 0, 0);
        }
    }

    // Reduce the 4 K-partials (32x64 tile). Waves 1..3 park partials in LDS
    // (tile reuse; 3 x 32 x 65 x 4 B = 24.96 KB <= 48 KB), wave 0 sums +
    // clamps + stores. C/D layout: col=lane&15, row=quad*4+reg.
    __syncthreads();
    if (w > 0) {
        float* red = (float*)smem + (w - 1) * (32 * 65);  // stride 65: no conflicts
#pragma unroll
        for (int ti = 0; ti < 2; ++ti)
#pragma unroll
            for (int tj = 0; tj < 4; ++tj)
#pragma unroll
                for (int r = 0; r < 4; ++r)
                    red[(ti * 16 + q * 4 + r) * 65 + tj * 16 + m] = acc[ti][tj][r];
    }
    __syncthreads();
    if (w == 0) {
        float* r0 = (float*)smem;
        float* r1 = r0 + 32 * 65;
        float* r2 = r1 + 32 * 65;
        float* ob = out + (size_t)b * (WIDTH * WIDTH);
#pragma unroll
        for (int ti = 0; ti < 2; ++ti)
#pragma unroll
            for (int tj = 0; tj < 4; ++tj)
#pragma unroll
                for (int r = 0; r < 4; ++r) {
                    int row = ti * 16 + q * 4 + r;       // local tile row 0..31
                    int col = tj * 16 + m;
                    int i = base + row - 2, j = col - 2; // image coords
                    if ((unsigned)i < WIDTH && (unsigned)j < WIDTH) {
                        float v = acc[ti][tj][r] + r0[row * 65 + col] +
                                  r1[row * 65 + col] + r2[row * 65 + col];
                        ob[i * WIDTH + j] = fminf(v, 1.0f);
                    }
                }
    }
}

extern "C" void kernel_launch(void* const* d_in, const int* in_sizes, int n_in,
                              void* d_out, int out_size, void* d_ws, size_t ws_size,
                              hipStream_t stream) {
    const float* x = (const float*)d_in[0];
    float* out = (float*)d_out;
    int B = in_sizes[0] / (LCURVES * 8);  // 256
    bezier_mfma_kernel<<<B * 2, 256, 0, stream>>>(x, out);
}

// Round 7
// 76.723 us; speedup vs baseline: 1.0982x; 1.0982x over previous
//
#include <hip/hip_runtime.h>

// BezierToImageLayer as a sparse-fill MFMA GEMM.
// result[b,i,j] = clamp(sum_k gx[k][i]*gy[k][j]) with k = 4800 splats:
// a 64x64x4800 f16 GEMM per sample. Gx/Gy are sparse per column and built in
// LDS with plain ds_write_b16 (each splat owns its k-column -> NO atomics).
//
// R7: byte-level R0 structure (the ONLY structure that passes: R0/R3/R4 = 3/3;
// all four restructures R1/R2/R5/R6 failed correctness unexplainably, so
// structural work is closed for this session). Two safe in-loop trims:
//  (1) 6-tap floor window -> 5-TAP ROUND-CENTERED window. Nearest dropped tap
//      is >=2.5 px from the gaussian center: weight <= exp(-(2.5/60)^2/2e-4)
//      = 1.7e-4 per splat-axis, accumulated ~1e-3 << 0.02 threshold. Saves
//      2 exp2 + 2 cvt + 4 ds_write per chunk, and since i0<=59 -> i0+4<=63,
//      ALL row min-clamps go away (R0 needed them for 59+5=64).
//  (2) incremental l,n update (ds=256=160+96, branchless wrap) replacing the
//      per-chunk magic-mul s%160, s/160.
// Diagnostic: if this ~10-15% issue-work cut moves dur_us < 2us, the kernel
// is pure chain-latency-bound at 1 wave/SIMD and this structure is at its
// ceiling (occupancy route empirically closed).
//
// Tile row r = image row r-2 (C rows 2..61 are the 60 output pixels).

#define WIDTH 60
#define LCURVES 160
#define NSAMP 30
#define NEG_INVA_LOG2E (-7213.4752f)   // -(1/alpha)*log2(e) = -5000*1.442695

typedef _Float16 half8 __attribute__((ext_vector_type(8)));
typedef float floatx4 __attribute__((ext_vector_type(4)));

__global__ __launch_bounds__(256) void bezier_mfma_kernel(
    const float* __restrict__ x, float* __restrict__ out) {
    // 4 waves x (Gx + Gy) x 64x64 f16 = 65536 B; reused as reduction buffer.
    __shared__ __align__(16) char smem[65536];

    const int tid = threadIdx.x;
    const int lane = tid & 63;
    const int w = tid >> 6;          // wave id 0..3
    const int b = blockIdx.x;
    const int m = lane & 15;         // fragment row/col within 16
    const int q = lane >> 4;         // quad 0..3

    // zero all tiles (4096 float4s)
    float4* sz = (float4*)smem;
#pragma unroll
    for (int i = 0; i < 16; ++i)
        sz[tid + 256 * i] = make_float4(0.f, 0.f, 0.f, 0.f);
    __syncthreads();

    _Float16* gx = (_Float16*)(smem + w * 16384);  // [64 rows][64 cols] swizzled
    _Float16* gy = gx + 4096;

    floatx4 acc[4][4];
#pragma unroll
    for (int ti = 0; ti < 4; ++ti)
#pragma unroll
        for (int tj = 0; tj < 4; ++tj)
            acc[ti][tj] = (floatx4){0.f, 0.f, 0.f, 0.f};

    const float* xb = x + (size_t)b * (LCURVES * 8);
    int prev_i0 = 0, prev_j0 = 0;   // first-iter zeroing hits already-zero cells

    // Incremental curve/sample indices for s = c*64 + lane, c += 4 (ds=256):
    // one divide at init, then branchless wrap (256 = 160 + 96).
    int l = (w * 64 + lane) % LCURVES;
    int n = (w * 64 + lane) / LCURVES;

    // 75 chunks of 64 splats; wave w takes chunks w, w+4, ... (disjoint K)
    for (int c = w; c < 75; c += 4) {
        const float4* cp = (const float4*)(xb + l * 8);
        float4 c0 = cp[0];  // x0 y0 x1 y1
        float4 c1 = cp[1];  // x2 y2 x3 y3

        // warped Bernstein basis (matches reference _bezier_basis)
        float tt = (float)n * (1.0f / NSAMP);
        tt = 2.0f * tt * tt * tt - 3.0f * tt * tt + 2.0f * tt;
        float tb = 1.0f - tt, t2 = tt * tt;
        float w0 = t2 * tt;
        float w1 = 3.0f * (t2 - w0);
        float w2 = 3.0f * tt * tb * tb;
        float w3 = tb * tb * tb;
        float X = w0 * c0.x + w1 * c0.z + w2 * c1.x + w3 * c1.z;
        float Y = w0 * c0.y + w1 * c0.w + w2 * c1.y + w3 * c1.w;

        // advance (l, n) for the next chunk (s += 256 = 160 + 96)
        {
            int wrap = (l + 96 >= LCURVES) ? 1 : 0;
            l += 96 - LCURVES * wrap;
            n += 1 + wrap;
        }

        // round-centered window base: covered taps within 2.5 px of center
        int i0 = (int)floorf(X * (float)WIDTH + 0.5f);
        int j0 = (int)floorf(Y * (float)WIDTH + 0.5f);
        i0 = min(max(i0, 0), 59);
        j0 = min(max(j0, 0), 59);

        // zero previous chunk's 10 cells (same lane, in-order DS -> safe),
        // then write this chunk's 10 tap weights. No other lane touches
        // column `lane`, so plain stores suffice. Rows i0..i0+4 <= 63:
        // no clamp needed.
#pragma unroll
        for (int a = 0; a < 5; ++a) {
            int rz = prev_i0 + a;
            gx[rz * 64 + (lane ^ ((rz & 7) << 3))] = (_Float16)0;
            int rz2 = prev_j0 + a;
            gy[rz2 * 64 + (lane ^ ((rz2 & 7) << 3))] = (_Float16)0;
        }
        float bx = (float)(i0 - 2) * (1.0f / WIDTH) - X;
        float by = (float)(j0 - 2) * (1.0f / WIDTH) - Y;
#pragma unroll
        for (int a = 0; a < 5; ++a) {
            float dx = bx + (float)a * (1.0f / WIDTH);
            float vx = __builtin_amdgcn_exp2f(dx * dx * NEG_INVA_LOG2E);
            int r = i0 + a;
            gx[r * 64 + (lane ^ ((r & 7) << 3))] = (_Float16)vx;
            float dy = by + (float)a * (1.0f / WIDTH);
            float vy = __builtin_amdgcn_exp2f(dy * dy * NEG_INVA_LOG2E);
            int r2 = j0 + a;
            gy[r2 * 64 + (lane ^ ((r2 & 7) << 3))] = (_Float16)vy;
        }
        prev_i0 = i0;
        prev_j0 = j0;

        // MFMA over this chunk's K=64: A[m][k]=gx(row m)[k], B[k][n]=gy(row n)[k]
        // A-frag: lane(m,q) holds k = kk*32 + q*8 + j ; swizzled col base =
        // 8*((kk*4+q) ^ (row&7)) -> contiguous 16B -> ds_read_b128.
#pragma unroll
        for (int kk = 0; kk < 2; ++kk) {
            half8 af[4], bf[4];
#pragma unroll
            for (int t = 0; t < 4; ++t) {
                int ra = t * 16 + m;
                af[t] = *(const half8*)&gx[ra * 64 + (((kk * 4 + q) ^ (ra & 7)) << 3)];
                bf[t] = *(const half8*)&gy[ra * 64 + (((kk * 4 + q) ^ (ra & 7)) << 3)];
            }
#pragma unroll
            for (int ti = 0; ti < 4; ++ti)
#pragma unroll
                for (int tj = 0; tj < 4; ++tj)
                    acc[ti][tj] = __builtin_amdgcn_mfma_f32_16x16x32_f16(
                        af[ti], bf[tj], acc[ti][tj], 0, 0, 0);
        }
    }

    // Reduce the 4 K-partials. Waves 1..3 park partials in LDS (tile reuse),
    // wave 0 sums + clamps + stores. C/D layout: col=lane&15, row=quad*4+reg.
    __syncthreads();
    if (w > 0) {
        float* red = (float*)smem + (w - 1) * (64 * 65);  // stride 65: no conflicts
#pragma unroll
        for (int ti = 0; ti < 4; ++ti)
#pragma unroll
            for (int tj = 0; tj < 4; ++tj)
#pragma unroll
                for (int r = 0; r < 4; ++r)
                    red[(ti * 16 + q * 4 + r) * 65 + tj * 16 + m] = acc[ti][tj][r];
    }
    __syncthreads();
    if (w == 0) {
        float* r0 = (float*)smem;
        float* r1 = r0 + 64 * 65;
        float* r2 = r1 + 64 * 65;
        float* ob = out + (size_t)b * (WIDTH * WIDTH);
#pragma unroll
        for (int ti = 0; ti < 4; ++ti)
#pragma unroll
            for (int tj = 0; tj < 4; ++tj)
#pragma unroll
                for (int r = 0; r < 4; ++r) {
                    int row = ti * 16 + q * 4 + r;
                    int col = tj * 16 + m;
                    int i = row - 2, j = col - 2;
                    if ((unsigned)i < WIDTH && (unsigned)j < WIDTH) {
                        float v = acc[ti][tj][r] + r0[row * 65 + col] +
                                  r1[row * 65 + col] + r2[row * 65 + col];
                        ob[i * WIDTH + j] = fminf(v, 1.0f);
                    }
                }
    }
}

extern "C" void kernel_launch(void* const* d_in, const int* in_sizes, int n_in,
                              void* d_out, int out_size, void* d_ws, size_t ws_size,
                              hipStream_t stream) {
    const float* x = (const float*)d_in[0];
    float* out = (float*)d_out;
    int B = in_sizes[0] / (LCURVES * 8);  // 256
    bezier_mfma_kernel<<<B, 256, 0, stream>>>(x, out);
}

// Round 8
// 75.980 us; speedup vs baseline: 1.1090x; 1.0098x over previous
//
#include <hip/hip_runtime.h>

// BezierToImageLayer as a sparse-fill MFMA GEMM.
// result[b,i,j] = clamp(sum_k gx[k][i]*gy[k][j]) with k = 4800 splats:
// a 64x64x4800 f16 GEMM per sample. Gx/Gy are sparse per column and built in
// LDS with plain ds_write_b16 (each splat owns its k-column -> NO atomics).
//
// R8: R7 structure byte-identical (the ONLY structure that passes: R0/R3/R4/
// R7 = 4/4; all four restructures failed correctness, structural work closed).
// Two chain-shortening trims inside the verified loop:
//  (1) FACTORED GAUSSIAN: w_a = exp(-(bx+a*d)^2/alpha) = A * B^a * K_a with
//      A=exp2(c*bx^2), B=exp2(2cd*bx), K_a compile-time. 2 exp2 per axis
//      instead of 5, and exp2 latency leaves the per-tap dependent path
//      (this kernel is chain-latency-bound: R7 showed issue cuts pay ~0.35x,
//      chain cuts should pay more). Worst-case ranges f32-safe
//      (bx in [-3.5d,-1.5d] -> B<=2^14.1, P<=3e9; rel err ~1e-6 << 2e-2).
//  (2) CACHED ZERO-ADDRESSES: the 10 zero-stores reuse last chunk's write
//      offsets from registers (fully unrolled -> static indexing, no
//      scratch) instead of recomputing swizzled addresses (~50 VALU/chunk).
//
// Tile row r = image row r-2 (C rows 2..61 are the 60 output pixels).

#define WIDTH 60
#define LCURVES 160
#define NSAMP 30
#define NEG_INVA_LOG2E (-7213.4752f)   // -(1/alpha)*log2(e) = -5000*1.442695
#define NEG_2D_LOG2E   (-240.449173f)  // NEG_INVA_LOG2E * 2/60
// K_a = exp2(NEG_INVA_LOG2E * a^2 / 3600) = exp(-a^2 / 0.72)
#define K1 0.24935221f
#define K2 0.0038659201f
#define K3 3.7266532e-6f
#define K4 2.2336982e-10f

typedef _Float16 half8 __attribute__((ext_vector_type(8)));
typedef float floatx4 __attribute__((ext_vector_type(4)));

__global__ __launch_bounds__(256) void bezier_mfma_kernel(
    const float* __restrict__ x, float* __restrict__ out) {
    // 4 waves x (Gx + Gy) x 64x64 f16 = 65536 B; reused as reduction buffer.
    __shared__ __align__(16) char smem[65536];

    const int tid = threadIdx.x;
    const int lane = tid & 63;
    const int w = tid >> 6;          // wave id 0..3
    const int b = blockIdx.x;
    const int m = lane & 15;         // fragment row/col within 16
    const int q = lane >> 4;         // quad 0..3

    // zero all tiles (4096 float4s)
    float4* sz = (float4*)smem;
#pragma unroll
    for (int i = 0; i < 16; ++i)
        sz[tid + 256 * i] = make_float4(0.f, 0.f, 0.f, 0.f);
    __syncthreads();

    _Float16* gx = (_Float16*)(smem + w * 16384);  // [64 rows][64 cols] swizzled
    _Float16* gy = gx + 4096;

    floatx4 acc[4][4];
#pragma unroll
    for (int ti = 0; ti < 4; ++ti)
#pragma unroll
        for (int tj = 0; tj < 4; ++tj)
            acc[ti][tj] = (floatx4){0.f, 0.f, 0.f, 0.f};

    const float* xb = x + (size_t)b * (LCURVES * 8);

    // Cached zero-offsets: init to rows 0..4 of the pre-zeroed tile so the
    // first iteration's zeroing is a harmless no-op.
    int azx[5], azy[5];
#pragma unroll
    for (int a = 0; a < 5; ++a) {
        azx[a] = a * 64 + (lane ^ ((a & 7) << 3));
        azy[a] = azx[a];
    }

    // Incremental curve/sample indices for s = c*64 + lane, c += 4 (ds=256):
    // one divide at init, then branchless wrap (256 = 160 + 96).
    int l = (w * 64 + lane) % LCURVES;
    int n = (w * 64 + lane) / LCURVES;

    // 75 chunks of 64 splats; wave w takes chunks w, w+4, ... (disjoint K)
    for (int c = w; c < 75; c += 4) {
        const float4* cp = (const float4*)(xb + l * 8);
        float4 c0 = cp[0];  // x0 y0 x1 y1
        float4 c1 = cp[1];  // x2 y2 x3 y3

        // warped Bernstein basis (matches reference _bezier_basis)
        float tt = (float)n * (1.0f / NSAMP);
        tt = 2.0f * tt * tt * tt - 3.0f * tt * tt + 2.0f * tt;
        float tb = 1.0f - tt, t2 = tt * tt;
        float w0 = t2 * tt;
        float w1 = 3.0f * (t2 - w0);
        float w2 = 3.0f * tt * tb * tb;
        float w3 = tb * tb * tb;
        float X = w0 * c0.x + w1 * c0.z + w2 * c1.x + w3 * c1.z;
        float Y = w0 * c0.y + w1 * c0.w + w2 * c1.y + w3 * c1.w;

        // advance (l, n) for the next chunk (s += 256 = 160 + 96)
        {
            int wrap = (l + 96 >= LCURVES) ? 1 : 0;
            l += 96 - LCURVES * wrap;
            n += 1 + wrap;
        }

        // round-centered window base: covered taps within 2.5 px of center
        int i0 = (int)floorf(X * (float)WIDTH + 0.5f);
        int j0 = (int)floorf(Y * (float)WIDTH + 0.5f);
        i0 = min(max(i0, 0), 59);
        j0 = min(max(j0, 0), 59);

        // zero previous chunk's 10 cells via cached offsets (same lane owns
        // the column, in-order DS -> safe).
#pragma unroll
        for (int a = 0; a < 5; ++a) {
            gx[azx[a]] = (_Float16)0;
            gy[azy[a]] = (_Float16)0;
        }

        // factored gaussian taps: w_a = A * B^a * K_a
        float bx = (float)(i0 - 2) * (1.0f / WIDTH) - X;
        float by = (float)(j0 - 2) * (1.0f / WIDTH) - Y;
        float Px = __builtin_amdgcn_exp2f(bx * bx * NEG_INVA_LOG2E);
        float Bx = __builtin_amdgcn_exp2f(bx * NEG_2D_LOG2E);
        float Py = __builtin_amdgcn_exp2f(by * by * NEG_INVA_LOG2E);
        float By = __builtin_amdgcn_exp2f(by * NEG_2D_LOG2E);
        const float Kt[5] = {1.0f, K1, K2, K3, K4};
#pragma unroll
        for (int a = 0; a < 5; ++a) {
            int r = i0 + a;                       // <= 63: no clamp needed
            int off = r * 64 + (lane ^ ((r & 7) << 3));
            gx[off] = (_Float16)(Px * Kt[a]);
            azx[a] = off;
            int r2 = j0 + a;
            int off2 = r2 * 64 + (lane ^ ((r2 & 7) << 3));
            gy[off2] = (_Float16)(Py * Kt[a]);
            azy[a] = off2;
            Px *= Bx;
            Py *= By;
        }

        // MFMA over this chunk's K=64: A[m][k]=gx(row m)[k], B[k][n]=gy(row n)[k]
        // A-frag: lane(m,q) holds k = kk*32 + q*8 + j ; swizzled col base =
        // 8*((kk*4+q) ^ (row&7)) -> contiguous 16B -> ds_read_b128.
#pragma unroll
        for (int kk = 0; kk < 2; ++kk) {
            half8 af[4], bf[4];
#pragma unroll
            for (int t = 0; t < 4; ++t) {
                int ra = t * 16 + m;
                af[t] = *(const half8*)&gx[ra * 64 + (((kk * 4 + q) ^ (ra & 7)) << 3)];
                bf[t] = *(const half8*)&gy[ra * 64 + (((kk * 4 + q) ^ (ra & 7)) << 3)];
            }
#pragma unroll
            for (int ti = 0; ti < 4; ++ti)
#pragma unroll
                for (int tj = 0; tj < 4; ++tj)
                    acc[ti][tj] = __builtin_amdgcn_mfma_f32_16x16x32_f16(
                        af[ti], bf[tj], acc[ti][tj], 0, 0, 0);
        }
    }

    // Reduce the 4 K-partials. Waves 1..3 park partials in LDS (tile reuse),
    // wave 0 sums + clamps + stores. C/D layout: col=lane&15, row=quad*4+reg.
    __syncthreads();
    if (w > 0) {
        float* red = (float*)smem + (w - 1) * (64 * 65);  // stride 65: no conflicts
#pragma unroll
        for (int ti = 0; ti < 4; ++ti)
#pragma unroll
            for (int tj = 0; tj < 4; ++tj)
#pragma unroll
                for (int r = 0; r < 4; ++r)
                    red[(ti * 16 + q * 4 + r) * 65 + tj * 16 + m] = acc[ti][tj][r];
    }
    __syncthreads();
    if (w == 0) {
        float* r0 = (float*)smem;
        float* r1 = r0 + 64 * 65;
        float* r2 = r1 + 64 * 65;
        float* ob = out + (size_t)b * (WIDTH * WIDTH);
#pragma unroll
        for (int ti = 0; ti < 4; ++ti)
#pragma unroll
            for (int tj = 0; tj < 4; ++tj)
#pragma unroll
                for (int r = 0; r < 4; ++r) {
                    int row = ti * 16 + q * 4 + r;
                    int col = tj * 16 + m;
                    int i = row - 2, j = col - 2;
                    if ((unsigned)i < WIDTH && (unsigned)j < WIDTH) {
                        float v = acc[ti][tj][r] + r0[row * 65 + col] +
                                  r1[row * 65 + col] + r2[row * 65 + col];
                        ob[i * WIDTH + j] = fminf(v, 1.0f);
                    }
                }
    }
}

extern "C" void kernel_launch(void* const* d_in, const int* in_sizes, int n_in,
                              void* d_out, int out_size, void* d_ws, size_t ws_size,
                              hipStream_t stream) {
    const float* x = (const float*)d_in[0];
    float* out = (float*)d_out;
    int B = in_sizes[0] / (LCURVES * 8);  // 256
    bezier_mfma_kernel<<<B, 256, 0, stream>>>(x, out);
}